// Round 20
// baseline (153.179 us; speedup 1.0000x reference)
//
#include <hip/hip_runtime.h>

#define IN_    16
#define HID_   50
#define T_     128
#define NCLS_  20
#define BPB_   8      // batches per block (8 of 16 MFMA cols real) -> grid 1024 = 4 blocks/CU
#define NTHR_  320    // 5 waves: 4 compute (3 M-tiles each) + 1 loader(+tile 12)
#define NROWS_ 16     // state rows allocated (8 real + 8 garbage-absorber)
#define KP_    104    // state row stride in halves = 52 dwords (4*13) -> conflict-free b128
#define KPW_   52     // stride in u32

typedef _Float16 half8 __attribute__((ext_vector_type(8)));
typedef float    f32x4 __attribute__((ext_vector_type(4)));
typedef unsigned int u32;

#define L2E_ 1.4426950408889634f
__device__ __forceinline__ u32 pkh2(float a, float b) {
    union { u32 v; _Float16 h[2]; } p; p.h[0] = (_Float16)a; p.h[1] = (_Float16)b; return p.v;
}
#define MFMA(A, B, C) __builtin_amdgcn_mfma_f32_16x16x32_f16((A), (B), (C), 0, 0, 0)
// activation-domain helpers (weights/bias PRE-SCALED by -log2e / -2log2e)
#define SIGS(v)  __builtin_amdgcn_rcpf(1.0f + __builtin_amdgcn_exp2f(v))
#define TANHS(v) fmaf(2.0f, __builtin_amdgcn_rcpf(1.0f + __builtin_amdgcn_exp2f(v)), -1.0f)

// A-fragment slice from GLOBAL. K layout: 0..15 = x rows (W_ih),
// 16..65 = h rows (W_hh), 66 = bias row, 67..95 = zero pad.
__device__ __forceinline__ half8 load_afrag(const float* __restrict__ W_ih,
                                            const float* __restrict__ W_hh,
                                            const float* __restrict__ b_ih,
                                            const float* __restrict__ b_hh,
                                            int s, int c, int q) {
    half8 r = {};
    const int u = s >> 2, kk = s & 3;
    if (u < HID_) {
        const float sc = (kk == 2) ? (-2.0f * L2E_) : (-L2E_);
        const int g = kk * HID_ + u;
        #pragma unroll
        for (int e = 0; e < 8; ++e) {
            const int k = c * 32 + q * 8 + e;
            float w = 0.f;
            if (k < IN_)                 w = W_ih[g * IN_ + k];
            else if (k < IN_ + HID_)     w = W_hh[g * HID_ + (k - IN_)];
            else if (k == IN_ + HID_)    w = b_ih[g] + b_hh[g];     // bias row
            r[e] = (_Float16)(w * sc);
        }
    }
    return r;
}

// (320, 5 waves/EU) -> ~102-VGPR cap; 3-tile wave demand ~80 fits (no R12 spill).
// 4 blocks/CU = 4 INDEPENDENT barrier domains — the de-phasing lever: R18's
// pipes were all <30% busy with the ~600-cyc step dependency chain exposed.
__global__ __launch_bounds__(NTHR_, 5)
void lstm_mfma(const float* __restrict__ x,
               const float* __restrict__ W_ih,
               const float* __restrict__ W_hh,
               const float* __restrict__ b_ih,
               const float* __restrict__ b_hh,
               const float* __restrict__ W_fc,
               const float* __restrict__ b_fc,
               float* __restrict__ out)
{
    // ONLY state in LDS: st[buf][row*KP_ + k]; rows 8..15 absorb garbage-col writes
    __shared__ __align__(16) _Float16 st[2][NROWS_ * KP_];   // 6.8 KB

    const int tid  = threadIdx.x;
    const int lane = tid & 63;
    const int wv   = tid >> 6;          // 0..4
    const int b0   = blockIdx.x * BPB_;
    const bool comp = (wv < 4);         // waves 0-3: 3 tiles; wave 4: loader + tile 12

    // ---- init state: zeros; half 66 of each row = 1.0 (bias row, BOTH buffers,
    //      never rewritten). h(0)=0; pad rows stay 0 forever.
    for (int idx = tid; idx < 2 * NROWS_ * KPW_; idx += NTHR_)
        ((u32*)st)[idx] = ((idx % KPW_) == 33) ? 0x00003C00u : 0u;  // halves 66,67

    const int q    = lane >> 4;
    const int bcol = lane & 15;                    // cols 8..15 garbage
    const int brow = bcol * KP_ + q * 8;           // B-frag half index (chunk 0)

    // ---- A-fragments from global -> regs (one time).
    //      waves 0-3: tiles 3wv..3wv+2 ; wave 4: tile 12.
    const int t0 = comp ? (3 * wv) : 12;
    const int s0 = t0 * 16 + (lane & 15);
    half8 A00 = load_afrag(W_ih, W_hh, b_ih, b_hh, s0, 0, q);
    half8 A01 = load_afrag(W_ih, W_hh, b_ih, b_hh, s0, 1, q);
    half8 A02 = load_afrag(W_ih, W_hh, b_ih, b_hh, s0, 2, q);
    half8 A10 = {}, A11 = {}, A12 = {}, A20 = {}, A21 = {}, A22 = {};
    if (comp) {
        A10 = load_afrag(W_ih, W_hh, b_ih, b_hh, s0 + 16, 0, q);
        A11 = load_afrag(W_ih, W_hh, b_ih, b_hh, s0 + 16, 1, q);
        A12 = load_afrag(W_ih, W_hh, b_ih, b_hh, s0 + 16, 2, q);
        A20 = load_afrag(W_ih, W_hh, b_ih, b_hh, s0 + 32, 0, q);
        A21 = load_afrag(W_ih, W_hh, b_ih, b_hh, s0 + 32, 1, q);
        A22 = load_afrag(W_ih, W_hh, b_ih, b_hh, s0 + 32, 2, q);
    }

    // per-lane units (C/D: col=lane&15, row=q*4+reg -> unit = tile*4+q)
    const int u0 = t0 * 4 + q;                     // wave4: 48..51 (48,49 real)
    const int u1 = u0 + 4;
    const int u2 = u0 + 8;
    float c0_ = 0.f, c1_ = 0.f, c2_ = 0.f;

    const int hrow0 = bcol * KP_ + IN_ + u0;       // garbage cols -> rows 8..15
    const int hrow1 = bcol * KP_ + IN_ + u1;
    const int hrow2 = bcol * KP_ + IN_ + u2;

    // ---- loader mapping (wave 4, lanes 0..31): 8 batches x 4 feature-quads
    const int lb = lane >> 2, fq = lane & 3;       // lb 0..15, real if <8
    const bool xl = (!comp) && (lb < BPB_);
    const float* xq = x + (size_t)(b0 + (xl ? lb : 0)) * (T_ * IN_) + 4 * fq;
    const int xo = lb * KPW_ + 2 * fq;             // u32 index

    float4 xr = {0.f, 0.f, 0.f, 0.f};
    __syncthreads();                               // init visible
    if (xl) {                                      // x(0) -> LDS, x(1) -> regs
        const float4 v = *(const float4*)xq;
        u32* d = (u32*)st[0];
        d[xo] = pkh2(v.x, v.y); d[xo + 1] = pkh2(v.z, v.w);
        xr = *(const float4*)(xq + IN_);
    }
    __syncthreads();                               // x(0) ready

    for (int t = 0; t < T_; ++t) {
        const _Float16* sc = st[t & 1];
        _Float16*       sn = st[(t & 1) ^ 1];

        const half8 B0 = *(const half8*)(sc + brow);
        const half8 B1 = *(const half8*)(sc + brow + 32);
        const half8 B2 = *(const half8*)(sc + brow + 64);
        const f32x4 Z = {0.f, 0.f, 0.f, 0.f};

        if (comp) {
            // 3 independent C-chains (ILP): 9 MFMA, B-frags shared
            f32x4 C0 = MFMA(A00, B0, Z);
            f32x4 C1 = MFMA(A10, B0, Z);
            f32x4 C2 = MFMA(A20, B0, Z);
            C0 = MFMA(A01, B1, C0);
            C1 = MFMA(A11, B1, C1);
            C2 = MFMA(A21, B1, C2);
            C0 = MFMA(A02, B2, C0);    // chunk 2 carries h-tails + bias row
            C1 = MFMA(A12, B2, C1);
            C2 = MFMA(A22, B2, C2);

            {   const float iv = SIGS(C0[0]), fv = SIGS(C0[1]);
                const float gv = TANHS(C0[2]), ov = SIGS(C0[3]);
                c0_ = fmaf(fv, c0_, iv * gv);
                sn[hrow0] = (_Float16)(ov * TANHS(c0_ * (-2.0f * L2E_))); }
            {   const float iv = SIGS(C1[0]), fv = SIGS(C1[1]);
                const float gv = TANHS(C1[2]), ov = SIGS(C1[3]);
                c1_ = fmaf(fv, c1_, iv * gv);
                sn[hrow1] = (_Float16)(ov * TANHS(c1_ * (-2.0f * L2E_))); }
            {   const float iv = SIGS(C2[0]), fv = SIGS(C2[1]);
                const float gv = TANHS(C2[2]), ov = SIGS(C2[3]);
                c2_ = fmaf(fv, c2_, iv * gv);
                sn[hrow2] = (_Float16)(ov * TANHS(c2_ * (-2.0f * L2E_))); }
        } else {
            // tile 12 (units 48,49 real)
            f32x4 C0 = MFMA(A00, B0, Z);
            C0 = MFMA(A01, B1, C0);
            C0 = MFMA(A02, B2, C0);
            const float iv = SIGS(C0[0]), fv = SIGS(C0[1]);
            const float gv = TANHS(C0[2]), ov = SIGS(C0[3]);
            c0_ = fmaf(fv, c0_, iv * gv);
            if (u0 < HID_) sn[hrow0] = (_Float16)(ov * TANHS(c0_ * (-2.0f * L2E_)));
            // x(t+1) from regs; prefetch x(t+2)
            if (xl && t + 1 < T_) {
                u32* d = (u32*)sn;
                d[xo] = pkh2(xr.x, xr.y); d[xo + 1] = pkh2(xr.z, xr.w);
            }
            if (xl && t + 2 < T_) xr = *(const float4*)(xq + (size_t)(t + 2) * IN_);
        }
        __syncthreads();               // ONE barrier per step (5 waves, 4 domains/CU)
    }

    // final h in st[0] (t=127 wrote nxt=0), fp16 rows 16..65 of each batch row
    const _Float16* hf = st[0];

    // ---- FC head: 8 batches x 20 classes (160 threads)
    if (tid < BPB_ * NCLS_) {
        const int b  = tid / NCLS_;
        const int cl = tid - b * NCLS_;
        float acc = b_fc[cl];
        #pragma unroll
        for (int j = 0; j < HID_; ++j) {
            const float hv = fmaxf((float)hf[b * KP_ + IN_ + j], 0.0f);  // relu
            acc = fmaf(hv, W_fc[cl * HID_ + j], acc);
        }
        out[(size_t)(b0 + b) * NCLS_ + cl] = acc;
    }
}

extern "C" void kernel_launch(void* const* d_in, const int* in_sizes, int n_in,
                              void* d_out, int out_size, void* d_ws, size_t ws_size,
                              hipStream_t stream) {
    const float* x    = (const float*)d_in[0];
    const float* W_ih = (const float*)d_in[1];
    const float* W_hh = (const float*)d_in[2];
    const float* b_ih = (const float*)d_in[3];
    const float* b_hh = (const float*)d_in[4];
    const float* W_fc = (const float*)d_in[5];
    const float* b_fc = (const float*)d_in[6];
    float* out = (float*)d_out;

    const int B = in_sizes[0] / (T_ * IN_);   // 8192
    dim3 grid(B / BPB_), block(NTHR_);
    hipLaunchKernelGGL(lstm_mfma, grid, block, 0, stream,
                       x, W_ih, W_hh, b_ih, b_hh, W_fc, b_fc, out);
}

// Round 21
// 96.224 us; speedup vs baseline: 1.5919x; 1.5919x over previous
//
#include <hip/hip_runtime.h>

#define IN_    16
#define HID_   50
#define T_     128
#define NCLS_  20
#define BPB_   16     // batches per block = MFMA N (full; no garbage lanes)
#define NTHR_  256    // 4 waves: 3 compute (4 M-tiles each) + 1 loader(+tile 12)
#define KP_    104    // state row stride in halves = 52 dwords (4*13) -> conflict-free b128
#define KPW_   52     // stride in u32

typedef _Float16 half8 __attribute__((ext_vector_type(8)));
typedef float    f32x4 __attribute__((ext_vector_type(4)));
typedef unsigned int u32;

#define L2E_ 1.4426950408889634f
__device__ __forceinline__ u32 pkh2(float a, float b) {
    union { u32 v; _Float16 h[2]; } p; p.h[0] = (_Float16)a; p.h[1] = (_Float16)b; return p.v;
}
#define MFMA(A, B, C) __builtin_amdgcn_mfma_f32_16x16x32_f16((A), (B), (C), 0, 0, 0)
// activation-domain helpers (weights/bias PRE-SCALED by -log2e / -2log2e)
#define SIGS(v)  __builtin_amdgcn_rcpf(1.0f + __builtin_amdgcn_exp2f(v))
#define TANHS(v) fmaf(2.0f, __builtin_amdgcn_rcpf(1.0f + __builtin_amdgcn_exp2f(v)), -1.0f)

// A-fragment slice from GLOBAL. K layout: 0..15 = x rows (W_ih),
// 16..65 = h rows (W_hh), 66 = bias row, 67..95 = zero pad.
__device__ __forceinline__ half8 load_afrag(const float* __restrict__ W_ih,
                                            const float* __restrict__ W_hh,
                                            const float* __restrict__ b_ih,
                                            const float* __restrict__ b_hh,
                                            int s, int c, int q) {
    half8 r = {};
    const int u = s >> 2, kk = s & 3;
    if (u < HID_) {
        const float sc = (kk == 2) ? (-2.0f * L2E_) : (-L2E_);
        const int g = kk * HID_ + u;
        #pragma unroll
        for (int e = 0; e < 8; ++e) {
            const int k = c * 32 + q * 8 + e;
            float w = 0.f;
            if (k < IN_)                 w = W_ih[g * IN_ + k];
            else if (k < IN_ + HID_)     w = W_hh[g * HID_ + (k - IN_)];
            else if (k == IN_ + HID_)    w = b_ih[g] + b_hh[g];     // bias row
            r[e] = (_Float16)(w * sc);
        }
    }
    return r;
}

// (256, 4 waves/EU) -> 128-VGPR cap; 4-tile wave demand ~95 fits.
// 3-tile->4-tile is the one lever that has paid twice (R11 103 -> R18 92):
// more independent chains per wave self-hide the step dependency latency.
__global__ __launch_bounds__(NTHR_, 4)
void lstm_mfma(const float* __restrict__ x,
               const float* __restrict__ W_ih,
               const float* __restrict__ W_hh,
               const float* __restrict__ b_ih,
               const float* __restrict__ b_hh,
               const float* __restrict__ W_fc,
               const float* __restrict__ b_fc,
               float* __restrict__ out)
{
    // ONLY state in LDS: st[buf][batch*KP_ + k]
    __shared__ __align__(16) _Float16 st[2][BPB_ * KP_];   // 6.8 KB

    const int tid  = threadIdx.x;
    const int lane = tid & 63;
    const int wv   = tid >> 6;          // 0..3
    const int b0   = blockIdx.x * BPB_;
    const bool comp = (wv < 3);         // waves 0-2: 4 tiles; wave 3: loader + tile 12

    // ---- init state: zeros; half 66 of each row = 1.0 (bias row, BOTH buffers,
    //      never rewritten). h(0)=0; pad rows stay 0 forever.
    for (int idx = tid; idx < 2 * BPB_ * KPW_; idx += NTHR_)
        ((u32*)st)[idx] = ((idx % KPW_) == 33) ? 0x00003C00u : 0u;  // halves 66,67

    const int q    = lane >> 4;
    const int bcol = lane & 15;
    const int brow = bcol * KP_ + q * 8;           // B-frag half index (chunk 0)

    // ---- A-fragments from global -> regs (one time).
    //      waves 0-2: tiles 4wv..4wv+3 ; wave 3: tile 12.
    const int t0 = comp ? (4 * wv) : 12;
    const int s0 = t0 * 16 + (lane & 15);
    half8 A00 = load_afrag(W_ih, W_hh, b_ih, b_hh, s0, 0, q);
    half8 A01 = load_afrag(W_ih, W_hh, b_ih, b_hh, s0, 1, q);
    half8 A02 = load_afrag(W_ih, W_hh, b_ih, b_hh, s0, 2, q);
    half8 A10 = {}, A11 = {}, A12 = {}, A20 = {}, A21 = {}, A22 = {};
    half8 A30 = {}, A31 = {}, A32 = {};
    if (comp) {
        A10 = load_afrag(W_ih, W_hh, b_ih, b_hh, s0 + 16, 0, q);
        A11 = load_afrag(W_ih, W_hh, b_ih, b_hh, s0 + 16, 1, q);
        A12 = load_afrag(W_ih, W_hh, b_ih, b_hh, s0 + 16, 2, q);
        A20 = load_afrag(W_ih, W_hh, b_ih, b_hh, s0 + 32, 0, q);
        A21 = load_afrag(W_ih, W_hh, b_ih, b_hh, s0 + 32, 1, q);
        A22 = load_afrag(W_ih, W_hh, b_ih, b_hh, s0 + 32, 2, q);
        A30 = load_afrag(W_ih, W_hh, b_ih, b_hh, s0 + 48, 0, q);
        A31 = load_afrag(W_ih, W_hh, b_ih, b_hh, s0 + 48, 1, q);
        A32 = load_afrag(W_ih, W_hh, b_ih, b_hh, s0 + 48, 2, q);
    }

    // per-lane units (C/D: col=lane&15, row=q*4+reg -> unit = tile*4+q)
    const int u0 = t0 * 4 + q;                     // wave3: 48..51 (48,49 real)
    const int u1 = u0 + 4;
    const int u2 = u0 + 8;
    const int u3 = u0 + 12;
    float c0_ = 0.f, c1_ = 0.f, c2_ = 0.f, c3_ = 0.f;

    const int hrow0 = bcol * KP_ + IN_ + u0;
    const int hrow1 = bcol * KP_ + IN_ + u1;
    const int hrow2 = bcol * KP_ + IN_ + u2;
    const int hrow3 = bcol * KP_ + IN_ + u3;

    // ---- loader mapping (wave 3): 64 lanes = 16 batches x 4 feature-quads
    const int lb = lane >> 2, fq = lane & 3;
    const float* xq = x + (size_t)(b0 + lb) * (T_ * IN_) + 4 * fq;
    const int xo = lb * KPW_ + 2 * fq;             // u32 index

    float4 xr = {0.f, 0.f, 0.f, 0.f};
    __syncthreads();                               // init visible
    if (!comp) {                                   // x(0) -> LDS, x(1) -> regs
        const float4 v = *(const float4*)xq;
        u32* d = (u32*)st[0];
        d[xo] = pkh2(v.x, v.y); d[xo + 1] = pkh2(v.z, v.w);
        xr = *(const float4*)(xq + IN_);
    }
    __syncthreads();                               // x(0) ready

    for (int t = 0; t < T_; ++t) {
        const _Float16* sc = st[t & 1];
        _Float16*       sn = st[(t & 1) ^ 1];

        const half8 B0 = *(const half8*)(sc + brow);
        const half8 B1 = *(const half8*)(sc + brow + 32);
        const half8 B2 = *(const half8*)(sc + brow + 64);
        const f32x4 Z = {0.f, 0.f, 0.f, 0.f};

        if (comp) {
            // 4 independent C-chains (ILP): 12 MFMA, B-frags shared
            f32x4 C0 = MFMA(A00, B0, Z);
            f32x4 C1 = MFMA(A10, B0, Z);
            f32x4 C2 = MFMA(A20, B0, Z);
            f32x4 C3 = MFMA(A30, B0, Z);
            C0 = MFMA(A01, B1, C0);
            C1 = MFMA(A11, B1, C1);
            C2 = MFMA(A21, B1, C2);
            C3 = MFMA(A31, B1, C3);
            C0 = MFMA(A02, B2, C0);    // chunk 2 carries h-tails + bias row
            C1 = MFMA(A12, B2, C1);
            C2 = MFMA(A22, B2, C2);
            C3 = MFMA(A32, B2, C3);

            {   const float iv = SIGS(C0[0]), fv = SIGS(C0[1]);
                const float gv = TANHS(C0[2]), ov = SIGS(C0[3]);
                c0_ = fmaf(fv, c0_, iv * gv);
                sn[hrow0] = (_Float16)(ov * TANHS(c0_ * (-2.0f * L2E_))); }
            {   const float iv = SIGS(C1[0]), fv = SIGS(C1[1]);
                const float gv = TANHS(C1[2]), ov = SIGS(C1[3]);
                c1_ = fmaf(fv, c1_, iv * gv);
                sn[hrow1] = (_Float16)(ov * TANHS(c1_ * (-2.0f * L2E_))); }
            {   const float iv = SIGS(C2[0]), fv = SIGS(C2[1]);
                const float gv = TANHS(C2[2]), ov = SIGS(C2[3]);
                c2_ = fmaf(fv, c2_, iv * gv);
                sn[hrow2] = (_Float16)(ov * TANHS(c2_ * (-2.0f * L2E_))); }
            {   const float iv = SIGS(C3[0]), fv = SIGS(C3[1]);
                const float gv = TANHS(C3[2]), ov = SIGS(C3[3]);
                c3_ = fmaf(fv, c3_, iv * gv);
                sn[hrow3] = (_Float16)(ov * TANHS(c3_ * (-2.0f * L2E_))); }
        } else {
            // tile 12 (units 48,49 real)
            f32x4 C0 = MFMA(A00, B0, Z);
            C0 = MFMA(A01, B1, C0);
            C0 = MFMA(A02, B2, C0);
            const float iv = SIGS(C0[0]), fv = SIGS(C0[1]);
            const float gv = TANHS(C0[2]), ov = SIGS(C0[3]);
            c0_ = fmaf(fv, c0_, iv * gv);
            if (u0 < HID_) sn[hrow0] = (_Float16)(ov * TANHS(c0_ * (-2.0f * L2E_)));
            // x(t+1) from regs; prefetch x(t+2)
            if (t + 1 < T_) {
                u32* d = (u32*)sn;
                d[xo] = pkh2(xr.x, xr.y); d[xo + 1] = pkh2(xr.z, xr.w);
            }
            if (t + 2 < T_) xr = *(const float4*)(xq + (size_t)(t + 2) * IN_);
        }
        __syncthreads();               // ONE barrier per step (4 waves)
    }

    // final h in st[0] (t=127 wrote nxt=0), fp16 rows 16..65
    const _Float16* hf = st[0];

    // ---- FC head: 16 batches x 20 classes (320 outputs, 256 threads strided)
    for (int p = tid; p < BPB_ * NCLS_; p += NTHR_) {
        const int b  = p / NCLS_;
        const int cl = p - b * NCLS_;
        float acc = b_fc[cl];
        #pragma unroll
        for (int j = 0; j < HID_; ++j) {
            const float hv = fmaxf((float)hf[b * KP_ + IN_ + j], 0.0f);  // relu
            acc = fmaf(hv, W_fc[cl * HID_ + j], acc);
        }
        out[(size_t)(b0 + b) * NCLS_ + cl] = acc;
    }
}

extern "C" void kernel_launch(void* const* d_in, const int* in_sizes, int n_in,
                              void* d_out, int out_size, void* d_ws, size_t ws_size,
                              hipStream_t stream) {
    const float* x    = (const float*)d_in[0];
    const float* W_ih = (const float*)d_in[1];
    const float* W_hh = (const float*)d_in[2];
    const float* b_ih = (const float*)d_in[3];
    const float* b_hh = (const float*)d_in[4];
    const float* W_fc = (const float*)d_in[5];
    const float* b_fc = (const float*)d_in[6];
    float* out = (float*)d_out;

    const int B = in_sizes[0] / (T_ * IN_);   // 8192
    dim3 grid(B / BPB_), block(NTHR_);
    hipLaunchKernelGGL(lstm_mfma, grid, block, 0, stream,
                       x, W_ih, W_hh, b_ih, b_hh, W_fc, b_fc, out);
}

// Round 22
// 90.593 us; speedup vs baseline: 1.6908x; 1.0622x over previous
//
#include <hip/hip_runtime.h>

#define IN_    16
#define HID_   50
#define T_     128
#define NCLS_  20
#define BPB_   16     // batches per block = MFMA N (full; no garbage lanes)
#define NTHR_  320    // 5 waves: 4 compute (3 M-tiles each) + 1 loader(+tile 12)
#define KP_    104    // state row stride in halves = 52 dwords (4*13) -> conflict-free b128
#define KPW_   52     // stride in u32

typedef _Float16 half8 __attribute__((ext_vector_type(8)));
typedef float    f32x4 __attribute__((ext_vector_type(4)));
typedef unsigned int u32;

#define L2E_ 1.4426950408889634f
__device__ __forceinline__ u32 pkh2(float a, float b) {
    union { u32 v; _Float16 h[2]; } p; p.h[0] = (_Float16)a; p.h[1] = (_Float16)b; return p.v;
}
#define MFMA(A, B, C) __builtin_amdgcn_mfma_f32_16x16x32_f16((A), (B), (C), 0, 0, 0)
// activation-domain helpers (weights/bias PRE-SCALED by -log2e / -2log2e)
#define SIGS(v)  __builtin_amdgcn_rcpf(1.0f + __builtin_amdgcn_exp2f(v))
#define TANHS(v) fmaf(2.0f, __builtin_amdgcn_rcpf(1.0f + __builtin_amdgcn_exp2f(v)), -1.0f)

// A-fragment slice from GLOBAL. K layout: 0..15 = x rows (W_ih),
// 16..65 = h rows (W_hh), 66 = bias row, 67..95 = zero pad.
__device__ __forceinline__ half8 load_afrag(const float* __restrict__ W_ih,
                                            const float* __restrict__ W_hh,
                                            const float* __restrict__ b_ih,
                                            const float* __restrict__ b_hh,
                                            int s, int c, int q) {
    half8 r = {};
    const int u = s >> 2, kk = s & 3;
    if (u < HID_) {
        const float sc = (kk == 2) ? (-2.0f * L2E_) : (-L2E_);
        const int g = kk * HID_ + u;
        #pragma unroll
        for (int e = 0; e < 8; ++e) {
            const int k = c * 32 + q * 8 + e;
            float w = 0.f;
            if (k < IN_)                 w = W_ih[g * IN_ + k];
            else if (k < IN_ + HID_)     w = W_hh[g * HID_ + (k - IN_)];
            else if (k == IN_ + HID_)    w = b_ih[g] + b_hh[g];     // bias row
            r[e] = (_Float16)(w * sc);
        }
    }
    return r;
}

// R18 structure (best: 92.4us) + T5 s_setprio: compute waves get scheduler
// priority through their MFMA+trans cluster over the loader wave's memory ops.
__global__ __launch_bounds__(NTHR_, 6)
void lstm_mfma(const float* __restrict__ x,
               const float* __restrict__ W_ih,
               const float* __restrict__ W_hh,
               const float* __restrict__ b_ih,
               const float* __restrict__ b_hh,
               const float* __restrict__ W_fc,
               const float* __restrict__ b_fc,
               float* __restrict__ out)
{
    // ONLY state in LDS: st[buf][batch*KP_ + k]
    __shared__ __align__(16) _Float16 st[2][BPB_ * KP_];   // 6.8 KB

    const int tid  = threadIdx.x;
    const int lane = tid & 63;
    const int wv   = tid >> 6;          // 0..4
    const int b0   = blockIdx.x * BPB_;
    const bool comp = (wv < 4);         // waves 0-3: 3 tiles; wave 4: loader + tile 12

    // ---- init state: zeros; half 66 of each row = 1.0 (bias row, BOTH buffers,
    //      never rewritten). h(0)=0; pad rows stay 0 forever.
    for (int idx = tid; idx < 2 * BPB_ * KPW_; idx += NTHR_)
        ((u32*)st)[idx] = ((idx % KPW_) == 33) ? 0x00003C00u : 0u;  // halves 66,67

    const int q    = lane >> 4;
    const int bcol = lane & 15;
    const int brow = bcol * KP_ + q * 8;           // B-frag half index (chunk 0)

    // ---- A-fragments from global -> regs (one time).
    //      waves 0-3: tiles 3wv..3wv+2 ; wave 4: tile 12.
    const int t0 = comp ? (3 * wv) : 12;
    const int s0 = t0 * 16 + (lane & 15);
    half8 A00 = load_afrag(W_ih, W_hh, b_ih, b_hh, s0, 0, q);
    half8 A01 = load_afrag(W_ih, W_hh, b_ih, b_hh, s0, 1, q);
    half8 A02 = load_afrag(W_ih, W_hh, b_ih, b_hh, s0, 2, q);
    half8 A10 = {}, A11 = {}, A12 = {}, A20 = {}, A21 = {}, A22 = {};
    if (comp) {
        A10 = load_afrag(W_ih, W_hh, b_ih, b_hh, s0 + 16, 0, q);
        A11 = load_afrag(W_ih, W_hh, b_ih, b_hh, s0 + 16, 1, q);
        A12 = load_afrag(W_ih, W_hh, b_ih, b_hh, s0 + 16, 2, q);
        A20 = load_afrag(W_ih, W_hh, b_ih, b_hh, s0 + 32, 0, q);
        A21 = load_afrag(W_ih, W_hh, b_ih, b_hh, s0 + 32, 1, q);
        A22 = load_afrag(W_ih, W_hh, b_ih, b_hh, s0 + 32, 2, q);
    }

    // per-lane units (C/D: col=lane&15, row=q*4+reg -> unit = tile*4+q)
    const int u0 = t0 * 4 + q;                     // wave4: 48..51 (48,49 real)
    const int u1 = u0 + 4;
    const int u2 = u0 + 8;
    float c0_ = 0.f, c1_ = 0.f, c2_ = 0.f;

    const int hrow0 = bcol * KP_ + IN_ + u0;
    const int hrow1 = bcol * KP_ + IN_ + u1;
    const int hrow2 = bcol * KP_ + IN_ + u2;

    // ---- loader mapping (wave 4): 64 lanes = 16 batches x 4 feature-quads
    const int lb = lane >> 2, fq = lane & 3;
    const float* xq = x + (size_t)(b0 + lb) * (T_ * IN_) + 4 * fq;
    const int xo = lb * KPW_ + 2 * fq;             // u32 index

    float4 xr = {0.f, 0.f, 0.f, 0.f};
    __syncthreads();                               // init visible
    if (!comp) {                                   // x(0) -> LDS, x(1) -> regs
        const float4 v = *(const float4*)xq;
        u32* d = (u32*)st[0];
        d[xo] = pkh2(v.x, v.y); d[xo + 1] = pkh2(v.z, v.w);
        xr = *(const float4*)(xq + IN_);
    }
    __syncthreads();                               // x(0) ready

    for (int t = 0; t < T_; ++t) {
        const _Float16* sc = st[t & 1];
        _Float16*       sn = st[(t & 1) ^ 1];

        const half8 B0 = *(const half8*)(sc + brow);
        const half8 B1 = *(const half8*)(sc + brow + 32);
        const half8 B2 = *(const half8*)(sc + brow + 64);
        const f32x4 Z = {0.f, 0.f, 0.f, 0.f};

        if (comp) {
            __builtin_amdgcn_s_setprio(1);         // T5: favor compute waves
            // 3 independent C-chains (ILP): 9 MFMA, B-frags shared
            f32x4 C0 = MFMA(A00, B0, Z);
            f32x4 C1 = MFMA(A10, B0, Z);
            f32x4 C2 = MFMA(A20, B0, Z);
            C0 = MFMA(A01, B1, C0);
            C1 = MFMA(A11, B1, C1);
            C2 = MFMA(A21, B1, C2);
            C0 = MFMA(A02, B2, C0);    // chunk 2 carries h-tails + bias row
            C1 = MFMA(A12, B2, C1);
            C2 = MFMA(A22, B2, C2);

            {   const float iv = SIGS(C0[0]), fv = SIGS(C0[1]);
                const float gv = TANHS(C0[2]), ov = SIGS(C0[3]);
                c0_ = fmaf(fv, c0_, iv * gv);
                sn[hrow0] = (_Float16)(ov * TANHS(c0_ * (-2.0f * L2E_))); }
            {   const float iv = SIGS(C1[0]), fv = SIGS(C1[1]);
                const float gv = TANHS(C1[2]), ov = SIGS(C1[3]);
                c1_ = fmaf(fv, c1_, iv * gv);
                sn[hrow1] = (_Float16)(ov * TANHS(c1_ * (-2.0f * L2E_))); }
            {   const float iv = SIGS(C2[0]), fv = SIGS(C2[1]);
                const float gv = TANHS(C2[2]), ov = SIGS(C2[3]);
                c2_ = fmaf(fv, c2_, iv * gv);
                sn[hrow2] = (_Float16)(ov * TANHS(c2_ * (-2.0f * L2E_))); }
            __builtin_amdgcn_s_setprio(0);
        } else {
            // tile 12 (units 48,49 real)
            f32x4 C0 = MFMA(A00, B0, Z);
            C0 = MFMA(A01, B1, C0);
            C0 = MFMA(A02, B2, C0);
            const float iv = SIGS(C0[0]), fv = SIGS(C0[1]);
            const float gv = TANHS(C0[2]), ov = SIGS(C0[3]);
            c0_ = fmaf(fv, c0_, iv * gv);
            if (u0 < HID_) sn[hrow0] = (_Float16)(ov * TANHS(c0_ * (-2.0f * L2E_)));
            // x(t+1) from regs; prefetch x(t+2)
            if (t + 1 < T_) {
                u32* d = (u32*)sn;
                d[xo] = pkh2(xr.x, xr.y); d[xo + 1] = pkh2(xr.z, xr.w);
            }
            if (t + 2 < T_) xr = *(const float4*)(xq + (size_t)(t + 2) * IN_);
        }
        __syncthreads();               // ONE barrier per step (5 waves)
    }

    // final h in st[0] (t=127 wrote nxt=0), fp16 rows 16..65
    const _Float16* hf = st[0];

    // ---- FC head: 16 batches x 20 classes = 320 threads (exact)
    {
        const int b  = tid / NCLS_;
        const int cl = tid - b * NCLS_;
        float acc = b_fc[cl];
        #pragma unroll
        for (int j = 0; j < HID_; ++j) {
            const float hv = fmaxf((float)hf[b * KP_ + IN_ + j], 0.0f);  // relu
            acc = fmaf(hv, W_fc[cl * HID_ + j], acc);
        }
        out[(size_t)(b0 + b) * NCLS_ + cl] = acc;
    }
}

extern "C" void kernel_launch(void* const* d_in, const int* in_sizes, int n_in,
                              void* d_out, int out_size, void* d_ws, size_t ws_size,
                              hipStream_t stream) {
    const float* x    = (const float*)d_in[0];
    const float* W_ih = (const float*)d_in[1];
    const float* W_hh = (const float*)d_in[2];
    const float* b_ih = (const float*)d_in[3];
    const float* b_hh = (const float*)d_in[4];
    const float* W_fc = (const float*)d_in[5];
    const float* b_fc = (const float*)d_in[6];
    float* out = (float*)d_out;

    const int B = in_sizes[0] / (T_ * IN_);   // 8192
    dim3 grid(B / BPB_), block(NTHR_);
    hipLaunchKernelGGL(lstm_mfma, grid, block, 0, stream,
                       x, W_ih, W_hh, b_ih, b_hh, W_fc, b_fc, out);
}